// Round 7
// baseline (400.356 us; speedup 1.0000x reference)
//
#include <hip/hip_runtime.h>
#include <hip/hip_bf16.h>

// GraphConvolution: x[B,N,D] fp32, W[K,D,O] fp32, COO edges per support (fp32 vals).
// out[b][n][k*O+o] = sum_{edges (r=n,c) in k} val * (x[b][c][:] @ W[k][:,o])
constexpr int B = 16, N = 10000, D = 128, O = 64, K = 3, E = 160000;
constexpr int BO = B * O;   // 1024
constexpr int KO = K * O;   // 192
constexpr int NPB = 8;      // n's per GEMM block
constexpr int G = 8;        // spmm bo-groups, pinned to XCDs via blockIdx%8
constexpr int ROWS = 8;     // rows per spmm block
constexpr int NCH = N / ROWS;  // 1250

using short8  = __attribute__((ext_vector_type(8))) short;
using floatx4 = __attribute__((ext_vector_type(4))) float;
using floatx2 = __attribute__((ext_vector_type(2))) float;
struct U4 { unsigned a, b, c, d; };

__device__ __forceinline__ float bf2f(unsigned short u) {
  return __uint_as_float(((unsigned int)u) << 16);
}
// fp32 -> bf16, round-half-up (max err 0.5 ulp)
__device__ __forceinline__ unsigned short f2bf(float f) {
  return (unsigned short)((__float_as_uint(f) + 0x8000u) >> 16);
}
__device__ __forceinline__ unsigned pkbf(float lo, float hi) {
  return ((__float_as_uint(lo) + 0x8000u) >> 16) |
         ((__float_as_uint(hi) + 0x8000u) & 0xFFFF0000u);
}

// ---------------------------------------------------------------------------
// Kernel 0: repack W[K,D,O] fp32 -> MFMA A-fragment order (m=o, k=d), bf16.
// ---------------------------------------------------------------------------
__global__ void wpack_kernel(const float* __restrict__ w, unsigned short* __restrict__ wp) {
  const int i = blockIdx.x * 64 + threadIdx.x;
  if (i >= K * 16 * 64) return;
  const int lane = i & 63;
  const int dd = (i >> 6) & 3;
  const int t4 = (i >> 8) & 3;
  const int k  = i >> 10;
  const int o  = t4 * 16 + (lane & 15);
  const int d0 = dd * 32 + (lane >> 4) * 8;
  unsigned short* dst = wp + (size_t)i * 8;
#pragma unroll
  for (int j = 0; j < 8; ++j)
    dst[j] = f2bf(w[((size_t)k * D + d0 + j) * O + o]);
}

// ---------------------------------------------------------------------------
// Kernel 1: MFMA GEMM. pre[kloc][n][b*64+o] = sum_d x[b][n][d]*W[k][d][o] (bf16)
// A = W-frag (m=o), B = x-frag (n=b); D: col=b, row=o_loc -> 8B stores.
// x loads are non-temporal (read-once; keep L2 clean for spmm).
// ---------------------------------------------------------------------------
__global__ __launch_bounds__(192) void gemm_mfma_kernel(
    const float* __restrict__ x, const unsigned short* __restrict__ wpk,
    unsigned short* __restrict__ pre, int kBase)
{
  const int t = threadIdx.x;
  const int kloc = t >> 6;
  const int k = kBase + kloc;
  const int lane = t & 63;
  const int col  = lane & 15;
  const int quad = lane >> 4;

  short8 wfr[4][4];             // [t4][dd]
#pragma unroll
  for (int t4 = 0; t4 < 4; ++t4)
#pragma unroll
    for (int dd = 0; dd < 4; ++dd)
      wfr[t4][dd] = *(const short8*)(wpk + (size_t)(((k * 4 + t4) * 4 + dd) * 64 + lane) * 8);

  const int n0 = blockIdx.x * NPB;
  const float* xbase = x + (size_t)col * N * D;   // B-frag n-axis = b = col

  for (int nn = 0; nn < NPB; ++nn) {
    const int n = n0 + nn;
    const float* xp = xbase + (size_t)n * D + quad * 8;
    short8 xfr[4];
#pragma unroll
    for (int dd = 0; dd < 4; ++dd) {
      const floatx4 lo = __builtin_nontemporal_load((const floatx4*)(xp + dd * 32));
      const floatx4 hi = __builtin_nontemporal_load((const floatx4*)(xp + dd * 32 + 4));
      U4 u;
      u.a = pkbf(lo[0], lo[1]); u.b = pkbf(lo[2], lo[3]);
      u.c = pkbf(hi[0], hi[1]); u.d = pkbf(hi[2], hi[3]);
      xfr[dd] = __builtin_bit_cast(short8, u);
    }

    floatx4 acc[4] = {};
#pragma unroll
    for (int dd = 0; dd < 4; ++dd)
#pragma unroll
      for (int t4 = 0; t4 < 4; ++t4)
        acc[t4] = __builtin_amdgcn_mfma_f32_16x16x32_bf16(wfr[t4][dd], xfr[dd], acc[t4], 0, 0, 0);

    unsigned short* pp = pre + (((size_t)kloc * N + n) << 10) + col * 64 + quad * 4;
#pragma unroll
    for (int t4 = 0; t4 < 4; ++t4) {
      uint2 pk2;
      pk2.x = pkbf(acc[t4][0], acc[t4][1]);
      pk2.y = pkbf(acc[t4][2], acc[t4][3]);
      *(uint2*)(pp + t4 * 16) = pk2;
    }
  }
}

// ---------------------------------------------------------------------------
// Kernel 2: per-row edge histogram
// ---------------------------------------------------------------------------
__global__ void hist_kernel(const int* __restrict__ row, int* __restrict__ cnt) {
  const int i = blockIdx.x * 256 + threadIdx.x;
  if (i >= K * E) return;
  const int k = i / E;
  atomicAdd(&cnt[k * N + row[i]], 1);
}

// ---------------------------------------------------------------------------
// Kernel 3: exclusive scan per support -> CSR offsets (cnt becomes cursor)
// ---------------------------------------------------------------------------
__global__ __launch_bounds__(1024) void scan_kernel(int* __restrict__ cnt,
                                                    int* __restrict__ offs) {
  const int k = blockIdx.x;
  const int t = threadIdx.x;
  const int lane = t & 63, wid = t >> 6;
  __shared__ int wt[16];
  __shared__ int sbase;
  if (t == 0) { sbase = 0; offs[k * (N + 1)] = 0; }
  __syncthreads();

  for (int c0 = 0; c0 < N; c0 += 1024) {
    const int i = c0 + t;
    const int v = (i < N) ? cnt[k * N + i] : 0;
    int incl = v;
#pragma unroll
    for (int st = 1; st < 64; st <<= 1) {
      const int u = __shfl_up(incl, st, 64);
      if (lane >= st) incl += u;
    }
    if (lane == 63) wt[wid] = incl;
    __syncthreads();
    if (wid == 0) {
      int wv = (lane < 16) ? wt[lane] : 0;
#pragma unroll
      for (int st = 1; st < 16; st <<= 1) {
        const int u = __shfl_up(wv, st, 64);
        if (lane >= st) wv += u;
      }
      if (lane < 16) wt[lane] = wv;
    }
    __syncthreads();
    const int base = sbase + ((wid > 0) ? wt[wid - 1] : 0);
    if (i < N) {
      offs[k * (N + 1) + i + 1] = base + incl;
      cnt[k * N + i] = base + incl - v;
    }
    __syncthreads();
    if (t == 0) sbase += wt[15];
    __syncthreads();
  }
}

// ---------------------------------------------------------------------------
// Kernel 4: scatter edges into CSR order
// ---------------------------------------------------------------------------
__global__ void scatter_kernel(const int* __restrict__ row, const int* __restrict__ col,
                               const float* __restrict__ vals,
                               int* __restrict__ cursor, int* __restrict__ scol,
                               float* __restrict__ sval) {
  const int i = blockIdx.x * 256 + threadIdx.x;
  if (i >= K * E) return;
  const int k = i / E;
  const int pos = atomicAdd(&cursor[k * N + row[i]], 1);
  scol[k * E + pos] = col[i];
  sval[k * E + pos] = vals[i];
}

// ---------------------------------------------------------------------------
// Kernel 5: CSR SpMM, XCD-partitioned by bo-slice (per-XCD pre footprint
// 2.56 MB < 4 MB L2). Streams (edge lists in, out stores) are NON-TEMPORAL so
// they cannot evict the pre slice. k-major block order: one support at a time.
// ---------------------------------------------------------------------------
__global__ __launch_bounds__(64) void spmm_kernel(
    const unsigned short* __restrict__ pre, const int* __restrict__ offs,
    const int* __restrict__ scol, const float* __restrict__ sval,
    float* __restrict__ out, int kBase)
{
  const int bid = blockIdx.x;
  const int g   = bid & 7;
  const int t2  = bid >> 3;
  const int nc  = t2 % NCH;
  const int kloc = t2 / NCH;            // k-major
  const int k = kBase + kloc;
  const int lane = threadIdx.x;

  const int bo = g * 128 + 2 * lane;    // 2 consecutive bo per lane
  const int b = bo >> 6;
  const int o = bo & 63;
  const unsigned short* pk = pre + (((size_t)kloc * N) << 10) + bo;
  const int* cj = scol + (size_t)k * E;
  const float* vj = sval + (size_t)k * E;
  const int* op = offs + k * (N + 1) + nc * ROWS;

  for (int r = 0; r < ROWS; ++r) {
    const int j0 = __builtin_amdgcn_readfirstlane(op[r]);
    const int j1 = __builtin_amdgcn_readfirstlane(op[r + 1]);
    float a0 = 0.f, a1 = 0.f;
    int j = j0;
    for (; j + 7 < j1; j += 8) {
      int c[8]; float v[8]; unsigned u[8];
#pragma unroll
      for (int i = 0; i < 8; ++i) {
        c[i] = __builtin_amdgcn_readfirstlane(__builtin_nontemporal_load(cj + j + i));
        v[i] = __builtin_nontemporal_load(vj + j + i);
      }
#pragma unroll
      for (int i = 0; i < 8; ++i)
        u[i] = *(const unsigned*)(pk + ((size_t)c[i] << 10));   // L2-cached gather
#pragma unroll
      for (int i = 0; i < 8; ++i) {
        a0 += v[i] * bf2f((unsigned short)(u[i] & 0xFFFFu));
        a1 += v[i] * bf2f((unsigned short)(u[i] >> 16));
      }
    }
    for (; j < j1; ++j) {
      const int c = __builtin_amdgcn_readfirstlane(__builtin_nontemporal_load(cj + j));
      const float v = __builtin_nontemporal_load(vj + j);
      const unsigned u = *(const unsigned*)(pk + ((size_t)c << 10));
      a0 += v * bf2f((unsigned short)(u & 0xFFFFu));
      a1 += v * bf2f((unsigned short)(u >> 16));
    }
    const int n = nc * ROWS + r;
    floatx2 st; st[0] = a0; st[1] = a1;
    __builtin_nontemporal_store(st, (floatx2*)(out + ((size_t)b * N + n) * KO + (size_t)k * O + o));
  }
}

// ---------------------------------------------------------------------------
extern "C" void kernel_launch(void* const* d_in, const int* in_sizes, int n_in,
                              void* d_out, int out_size, void* d_ws, size_t ws_size,
                              hipStream_t stream) {
  const float* x    = (const float*)d_in[0];
  const float* w    = (const float*)d_in[1];
  const float* vals = (const float*)d_in[2];
  const int* row    = (const int*)d_in[3];
  const int* col    = (const int*)d_in[4];
  float* out        = (float*)d_out;

  char* p = (char*)d_ws;
  int* offs = (int*)p;            p += ((size_t)K * (N + 1) * 4 + 15) & ~(size_t)15;
  int* cnt  = (int*)p;            p += (size_t)K * N * 4;
  int* scol = (int*)p;            p += (size_t)K * E * 4;
  float* sval = (float*)p;        p += (size_t)K * E * 4;
  unsigned short* wpk = (unsigned short*)p; p += (size_t)K * 16 * 64 * 8 * 2;
  unsigned short* pre = (unsigned short*)p;
  const size_t fixed = (size_t)(p - (char*)d_ws);
  const size_t preFull = (size_t)K * N * BO * 2;
  const bool full = ws_size >= fixed + preFull;  // ws_size constant across calls

  (void)hipMemsetAsync(cnt, 0, (size_t)K * N * 4, stream);

  wpack_kernel<<<48, 64, 0, stream>>>(w, wpk);
  const int eb = (K * E + 255) / 256;
  hist_kernel<<<eb, 256, 0, stream>>>(row, cnt);
  scan_kernel<<<K, 1024, 0, stream>>>(cnt, offs);
  scatter_kernel<<<eb, 256, 0, stream>>>(row, col, vals, cnt, scol, sval);

  if (full) {
    gemm_mfma_kernel<<<N / NPB, 64 * K, 0, stream>>>(x, wpk, pre, 0);
    spmm_kernel<<<K * NCH * G, 64, 0, stream>>>(pre, offs, scol, sval, out, 0);
  } else {
    for (int k = 0; k < K; ++k) {
      gemm_mfma_kernel<<<N / NPB, 64, 0, stream>>>(x, wpk, pre, k);
      spmm_kernel<<<NCH * G, 64, 0, stream>>>(pre, offs, scol, sval, out, k);
    }
  }
  (void)in_sizes; (void)n_in; (void)out_size;
}